// Round 2
// baseline (413.324 us; speedup 1.0000x reference)
//
#include <hip/hip_runtime.h>

// KAN Convolutional Layer, fp32, MI355X. Round 2.
// x (16,32,64,64) f32, base_w (8,9), spline_w (8,9,8), spline_scaler (8,9)
// out (16, 256, 62, 62) f32.
//
// Structure:
//  - fold_weights: wf[n][k][0]=base_w, wf[n][k][1+s]=spline_w*scaler  (648 f32 in d_ws)
//  - main kernel: per (b,c) plane, strips of 16 output rows per 256-thread block.
//    Stage per-pixel 9-feature vector (silu + dense 8-wide cubic B-spline basis)
//    into LDS as AoS stride-9 (gcd(9,32)=1 -> conflict-free).
//    Each thread computes 4 column-stacked outputs x 8 convs: 2592 FMAs with
//    wave-uniform (s_load) weight operands, ~160 LDS dwords read.

constexpr int Hh = 64, Ww = 64;
constexpr int Ho = 62, Wo = 62;
constexpr int L  = Ho * Wo;          // 3844
constexpr int NC = 8;                // n_convs
constexpr int RPB = 16;              // output rows per block
constexpr int IR  = RPB + 2;         // staged input rows (max)
constexpr int NPX = IR * Ww;         // 1152 staged pixels (max)
constexpr int FS  = 9;               // features per pixel: silu + 8 basis

__global__ __launch_bounds__(128)
void fold_weights(const float* __restrict__ bw, const float* __restrict__ sw,
                  const float* __restrict__ scl, float* __restrict__ wf)
{
    int i = threadIdx.x;             // n*9+k, 0..71
    if (i < 72) {
        float sc = scl[i];
        wf[i * FS + 0] = bw[i];
#pragma unroll
        for (int s = 0; s < 8; s++) wf[i * FS + 1 + s] = sw[i * 8 + s] * sc;
    }
}

__global__ __launch_bounds__(256)
void kan_conv_kernel(const float* __restrict__ x,
                     const float* __restrict__ wf,
                     float* __restrict__ out)
{
    __shared__ float fsh[NPX * FS];  // 41472 B

    const int strip = blockIdx.x & 3;
    const int bc    = blockIdx.x >> 2;       // b*32 + c
    const int s0    = strip * RPB;           // first output row of this strip

    // ---- feature stage: silu + dense cubic B-spline basis per staged pixel ----
    const int stage_rows = (s0 + IR <= Hh) ? IR : (Hh - s0);  // 18, last strip 16
    const int npx = stage_rows * Ww;
    const float* xp = x + (size_t)bc * (Hh * Ww) + (size_t)s0 * Ww;

    for (int p = threadIdx.x; p < npx; p += 256) {
        float v  = xp[p];
        float sv = v / (1.0f + __expf(-v));       // silu
        const int base = p * FS;
        fsh[base] = sv;
#pragma unroll
        for (int f = 1; f < FS; f++) fsh[base + f] = 0.0f;

        // uniform cubic B-spline closed form; knots (i-3)*0.4-1 -> u=(v+2.2)*2.5
        float u  = (v + 2.2f) * 2.5f;
        float fj = floorf(u);
        float t  = u - fj;
        int   j  = (int)fj;
        float om = 1.0f - t;
        float t2 = t * t;
        float w3 = t * t2 * (1.0f / 6.0f);
        float w0 = om * om * om * (1.0f / 6.0f);
        float w1 = fmaf(t2, fmaf(t, 0.5f, -1.0f), 2.0f / 3.0f); // (3t^3-6t^2+4)/6
        float w2 = 1.0f - w0 - w1 - w3;
        int jm3 = j - 3;
        if ((unsigned)(jm3 + 0) < 8u) fsh[base + 1 + jm3 + 0] = w0;
        if ((unsigned)(jm3 + 1) < 8u) fsh[base + 1 + jm3 + 1] = w1;
        if ((unsigned)(jm3 + 2) < 8u) fsh[base + 1 + jm3 + 2] = w2;
        if ((unsigned)(jm3 + 3) < 8u) fsh[base + 1 + jm3 + 3] = w3;
    }
    __syncthreads();

    // ---- conv stage: each thread = 1 column x 4 output rows x 8 convs ----
    const int wv = threadIdx.x >> 6;   // wave -> row group (4 rows)
    const int ln = threadIdx.x & 63;   // lane -> output column
    if (ln >= Wo) return;              // no barriers after this point

    float acc[4][NC];
#pragma unroll
    for (int j = 0; j < 4; j++)
#pragma unroll
        for (int n = 0; n < NC; n++) acc[j][n] = 0.0f;

#pragma unroll
    for (int ir = 0; ir < 6; ir++) {           // local input rows wv*4 .. wv*4+5
        float ft[3][FS];
#pragma unroll
        for (int kw = 0; kw < 3; kw++) {
            const int pb = ((wv * 4 + ir) * Ww + ln + kw) * FS;
#pragma unroll
            for (int s = 0; s < FS; s++) ft[kw][s] = fsh[pb + s];
        }
#pragma unroll
        for (int kh = 0; kh < 3; kh++) {
            const int j = ir - kh;             // output row fed by this input row
            if (j < 0 || j > 3) continue;      // resolved at compile time
#pragma unroll
            for (int kw = 0; kw < 3; kw++) {
                const int k = kh * 3 + kw;
#pragma unroll
                for (int s = 0; s < FS; s++) {
                    const float f = ft[kw][s];
#pragma unroll
                    for (int n = 0; n < NC; n++)
                        acc[j][n] = fmaf(f, wf[(n * 9 + k) * FS + s], acc[j][n]);
                }
            }
        }
    }

    // ---- stores: coalesced per (row, conv) plane ----
#pragma unroll
    for (int j = 0; j < 4; j++) {
        const int orow = s0 + wv * 4 + j;
        if (orow < Ho) {
            const size_t ob = ((size_t)bc * NC) * L + (size_t)orow * Wo + ln;
#pragma unroll
            for (int n = 0; n < NC; n++) out[ob + (size_t)n * L] = acc[j][n];
        }
    }
}

extern "C" void kernel_launch(void* const* d_in, const int* in_sizes, int n_in,
                              void* d_out, int out_size, void* d_ws, size_t ws_size,
                              hipStream_t stream) {
    const float* x   = (const float*)d_in[0];
    const float* bw  = (const float*)d_in[1];
    const float* sw  = (const float*)d_in[2];
    const float* scl = (const float*)d_in[3];
    float* wf  = (float*)d_ws;                 // 648 floats
    float* out = (float*)d_out;

    fold_weights<<<1, 128, 0, stream>>>(bw, sw, scl, wf);

    const int planes = in_sizes[0] / (Hh * Ww);   // 512
    dim3 grid(planes * 4);                        // 2048 blocks
    kan_conv_kernel<<<grid, 256, 0, stream>>>(x, wf, out);
}

// Round 3
// 111.061 us; speedup vs baseline: 3.7216x; 3.7216x over previous
//
#include <hip/hip_runtime.h>

// KAN Convolutional Layer, fp32, MI355X. Round 3.
// x (16,32,64,64) f32 -> out (16, 256, 62, 62) f32.
//
// R2 failure: per-FMA global weight reads were per-lane VMEM in a 40KB
// unrolled body -> latency + I-cache bound (409us). Fix: weights folded into
// LDS once per block; rolled 9-tap loop stages each tap's 72 weights into
// VGPRs via broadcast ds_read_b128; 4 row-stacked outputs amortize them.

constexpr int Hh = 64, Ww = 64;
constexpr int Ho = 62, Wo = 62;
constexpr int L  = Ho * Wo;          // 3844
constexpr int NC = 8;                // n_convs
constexpr int RPB = 16;              // output rows per block (4 waves x 4 rows)
constexpr int IR  = RPB + 2;         // staged input rows (max 18)
constexpr int FS  = 9;               // features/pixel: silu + 8 basis
constexpr int NPX = IR * Ww;         // 1152
constexpr int WTOT = 9 * FS * NC;    // 648 folded weights

__global__ __launch_bounds__(256, 3)
void kan_conv_kernel(const float* __restrict__ x,
                     const float* __restrict__ base_w,
                     const float* __restrict__ spline_w,
                     const float* __restrict__ scl,
                     float* __restrict__ out)
{
    __shared__ float fsh[NPX * FS];              // 41472 B, AoS stride-9
    __shared__ __align__(16) float wsh[WTOT];    // 2592 B, [tap][feat][conv]

    const int strip = blockIdx.x & 3;
    const int bc    = blockIdx.x >> 2;           // b*32 + c
    const int s0    = strip * RPB;               // first output row of strip

    // ---- fold weights into LDS: wsh[k*72 + f*8 + n] ----
    for (int i = threadIdx.x; i < WTOT; i += 256) {
        const int n = i & 7;
        const int f = (i >> 3) % FS;
        const int k = i / (FS * NC);
        const int m = n * 9 + k;
        wsh[i] = (f == 0) ? base_w[m] : spline_w[m * 8 + (f - 1)] * scl[m];
    }

    // ---- feature stage: silu + dense cubic B-spline basis per staged pixel ----
    const int stage_rows = (s0 + IR <= Hh) ? IR : (Hh - s0);  // 18 (last: 16)
    const int npx = stage_rows * Ww;
    const float* xp = x + (size_t)bc * (Hh * Ww) + (size_t)s0 * Ww;

    for (int p = threadIdx.x; p < npx; p += 256) {
        float v  = xp[p];
        float sv = v / (1.0f + __expf(-v));       // silu
        const int base = p * FS;
        fsh[base] = sv;
#pragma unroll
        for (int f = 1; f < FS; f++) fsh[base + f] = 0.0f;

        // uniform cubic B-spline closed form; knots (i-3)*0.4-1 -> u=(v+2.2)*2.5
        float u  = (v + 2.2f) * 2.5f;
        float fj = floorf(u);
        float t  = u - fj;
        int   j  = (int)fj;
        float om = 1.0f - t;
        float t2 = t * t;
        float w3 = t * t2 * (1.0f / 6.0f);
        float w0 = om * om * om * (1.0f / 6.0f);
        float w1 = fmaf(t2, fmaf(t, 0.5f, -1.0f), 2.0f / 3.0f); // (3t^3-6t^2+4)/6
        float w2 = 1.0f - w0 - w1 - w3;
        const int jm3 = j - 3;
        if ((unsigned)(jm3 + 0) < 8u) fsh[base + 1 + jm3 + 0] = w0;
        if ((unsigned)(jm3 + 1) < 8u) fsh[base + 1 + jm3 + 1] = w1;
        if ((unsigned)(jm3 + 2) < 8u) fsh[base + 1 + jm3 + 2] = w2;
        if ((unsigned)(jm3 + 3) < 8u) fsh[base + 1 + jm3 + 3] = w3;
    }
    __syncthreads();

    // ---- conv stage: wave wv -> 4 output rows, lane -> column ----
    const int wv = threadIdx.x >> 6;
    const int ln = threadIdx.x & 63;

    if (ln < Wo) {
        float acc[4][NC];
#pragma unroll
        for (int j = 0; j < 4; j++)
#pragma unroll
            for (int n = 0; n < NC; n++) acc[j][n] = 0.0f;

#pragma unroll 1                       // keep body ~3KB, well inside I-cache
        for (int k = 0; k < 9; k++) {
            const int kh = k / 3;
            const int kw = k - kh * 3;

            // stage this tap's 72 weights: broadcast ds_read_b128 x18
            float4 w4[18];
            const float4* wp = (const float4*)&wsh[k * 72];
#pragma unroll
            for (int t = 0; t < 18; t++) w4[t] = wp[t];

#pragma unroll
            for (int j = 0; j < 4; j++) {
                const int pb = ((wv * 4 + j + kh) * Ww + ln + kw) * FS;
                float ft[FS];
#pragma unroll
                for (int f = 0; f < FS; f++) ft[f] = fsh[pb + f];

#pragma unroll
                for (int f = 0; f < FS; f++) {
                    const float4 wa = w4[f * 2];
                    const float4 wb = w4[f * 2 + 1];
                    acc[j][0] = fmaf(ft[f], wa.x, acc[j][0]);
                    acc[j][1] = fmaf(ft[f], wa.y, acc[j][1]);
                    acc[j][2] = fmaf(ft[f], wa.z, acc[j][2]);
                    acc[j][3] = fmaf(ft[f], wa.w, acc[j][3]);
                    acc[j][4] = fmaf(ft[f], wb.x, acc[j][4]);
                    acc[j][5] = fmaf(ft[f], wb.y, acc[j][5]);
                    acc[j][6] = fmaf(ft[f], wb.z, acc[j][6]);
                    acc[j][7] = fmaf(ft[f], wb.w, acc[j][7]);
                }
            }
        }

        // ---- stores: coalesced per (row, conv) plane ----
#pragma unroll
        for (int j = 0; j < 4; j++) {
            const int orow = s0 + wv * 4 + j;
            if (orow < Ho) {
                const size_t ob = (size_t)bc * NC * L + (size_t)orow * Wo + ln;
#pragma unroll
                for (int n = 0; n < NC; n++) out[ob + (size_t)n * L] = acc[j][n];
            }
        }
    }
}

extern "C" void kernel_launch(void* const* d_in, const int* in_sizes, int n_in,
                              void* d_out, int out_size, void* d_ws, size_t ws_size,
                              hipStream_t stream) {
    const float* x   = (const float*)d_in[0];
    const float* bw  = (const float*)d_in[1];
    const float* sw  = (const float*)d_in[2];
    const float* scl = (const float*)d_in[3];
    float* out = (float*)d_out;

    const int planes = in_sizes[0] / (Hh * Ww);   // 512
    dim3 grid(planes * 4);                        // 2048 blocks
    kan_conv_kernel<<<grid, 256, 0, stream>>>(x, bw, sw, scl, out);
}